// Round 5
// baseline (99.977 us; speedup 1.0000x reference)
//
#include <hip/hip_runtime.h>
#include <math.h>

#define BN 12
#define HG 28
#define WG 60
#define LL 1680      // HG*WG
#define CC 128
#define P2 20
#define HID 256
#define NPTS (BN * LL * P2)  // 403200
#define NPB 64               // points per block in gemm kernel
#define NWG (NPTS / NPB)     // 6300
#define NQB 4                // queries per block (mid fallback)
#define NP (NQB * P2)

static constexpr size_t OUT_CAM_OFF = (size_t)BN * LL * P2 * CC;              // 51609600
static constexpr size_t OUT_PTS_OFF = OUT_CAM_OFF + (size_t)BN * LL * P2 * 2; // 52416000

typedef short v8s __attribute__((ext_vector_type(8)));
typedef float v4f __attribute__((ext_vector_type(4)));
typedef unsigned long long u64;

__device__ __forceinline__ unsigned short f2bf(float f) {
  unsigned x = __float_as_uint(f);
  unsigned r = (x + 0x7FFFu + ((x >> 16) & 1u)) >> 16;
  return (unsigned short)r;
}

// ---------------- transpose img_features (BN,C,L) -> (BN,L,C) ----------------
__global__ __launch_bounds__(256) void transpose_feat_k(const float* __restrict__ in,
                                                        float* __restrict__ out) {
  __shared__ float tile[64][65];
  const int bn = blockIdx.z;
  const int c0 = blockIdx.y * 64;
  const int l0 = blockIdx.x * 64;
  const int t = threadIdx.x;
  {
    const int lx = t & 63;
    const int cy = t >> 6;
#pragma unroll
    for (int i = 0; i < 64; i += 4) {
      const int c = c0 + cy + i;
      const int l = l0 + lx;
      float v = 0.f;
      if (l < LL) v = in[((size_t)bn * CC + c) * LL + l];
      tile[cy + i][lx] = v;
    }
  }
  __syncthreads();
  {
    const int cx = t & 63;
    const int ly = t >> 6;
#pragma unroll
    for (int i = 0; i < 64; i += 4) {
      const int l = l0 + ly + i;
      const int c = c0 + cx;
      if (l < LL) out[((size_t)bn * LL + l) * CC + c] = tile[cx][ly + i];
    }
  }
}

// ---------------- pack W2 (256x128 f32) into bf16 B-fragment order ----------------
__global__ __launch_bounds__(256) void pack_w2_k(const float* __restrict__ W2,
                                                 unsigned short* __restrict__ W2bf) {
  const int t = blockIdx.x * 256 + threadIdx.x;
  if (t >= 4096) return;
  const int lane = t & 63;
  const int ks = (t >> 6) & 7;
  const int cg = t >> 9;
  const int col = cg * 16 + (lane & 15);
  const int kb = ks * 32 + (lane >> 4) * 8;
  v8s r;
#pragma unroll
  for (int e = 0; e < 8; ++e) r[e] = (short)f2bf(W2[(size_t)(kb + e) * CC + col]);
  *(v8s*)(W2bf + (size_t)t * 8) = r;
}

// ---------------- kernel A: geometry, cam/pts outputs, per-point records ----------------
__global__ __launch_bounds__(256) void geom_k(const float* __restrict__ means3D,
                                              const float* __restrict__ dvec,
                                              const float* __restrict__ cov3D,
                                              const float* __restrict__ l2i,
                                              float* __restrict__ out,
                                              u64* __restrict__ off8,
                                              float4* __restrict__ w4,
                                              float4* __restrict__ pn4) {
  const int pid = blockIdx.x * 256 + threadIdx.x;
  if (pid >= NPTS) return;
  const unsigned qg = (unsigned)pid / P2;
  const int p = pid - (int)qg * P2;
  const unsigned bn = qg / LL;

  const size_t base3 = (size_t)qg * 3;
  const float m0 = means3D[base3 + 0], m1 = means3D[base3 + 1], m2 = means3D[base3 + 2];
  const float d0 = dvec[base3 + 0], d1 = dvec[base3 + 1], d2 = dvec[base3 + 2];
  const float* cv = cov3D + (size_t)qg * 9;
  const float q = d0 * (cv[0] * d0 + cv[1] * d1 + cv[2] * d2) +
                  d1 * (cv[3] * d0 + cv[4] * d1 + cv[5] * d2) +
                  d2 * (cv[6] * d0 + cv[7] * d1 + cv[8] * d2);
  const float s = sqrtf(q);
  const int k = p >> 2, j = p & 3;
  const float a = (-1.5f + 0.75f * (float)k) * s;     // lin5[k]*sqrt(q)
  const float tt = -0.5f + (1.0f / 3.0f) * (float)j;  // linP[j]
  const float px = m0 + a * d0 + tt * d1;
  const float py = m1 + a * d1 - tt * d0;
  const float pz = m2 + a * d2;
  const float* M = l2i + (size_t)bn * 16;
  const float cx = M[0] * px + M[1] * py + M[2] * pz + M[3];
  const float cy = M[4] * px + M[5] * py + M[6] * pz + M[7];
  const float cz = M[8] * px + M[9] * py + M[10] * pz + M[11];
  const float homo = fmaxf(cz, 1e-6f);
  const float u = cx / homo;
  const float v = cy / homo;

  *(float2*)(out + OUT_CAM_OFF + (size_t)pid * 2) = make_float2(u, v);
  float* ptso = out + OUT_PTS_OFF + (size_t)pid * 3;
  ptso[0] = px;
  ptso[1] = py;
  ptso[2] = pz;

  const float x = u * 0.125f - 0.5f;
  const float y = v * 0.125f - 0.5f;
  const float x0f = floorf(x), y0f = floorf(y);
  const float wx = x - x0f, wy = y - y0f;
  const bool vx0 = (x0f >= 0.f) && (x0f < (float)WG);
  const bool vx1 = (x0f + 1.f >= 0.f) && (x0f + 1.f < (float)WG);
  const bool vy0 = (y0f >= 0.f) && (y0f < (float)HG);
  const bool vy1 = (y0f + 1.f >= 0.f) && (y0f + 1.f < (float)HG);
  const unsigned ix0 = (unsigned)(int)fminf(fmaxf(x0f, 0.f), (float)(WG - 1));
  const unsigned ix1 = (unsigned)(int)fminf(fmaxf(x0f + 1.f, 0.f), (float)(WG - 1));
  const unsigned iy0 = (unsigned)(int)fminf(fmaxf(y0f, 0.f), (float)(HG - 1));
  const unsigned iy1 = (unsigned)(int)fminf(fmaxf(y0f + 1.f, 0.f), (float)(HG - 1));
  const u64 o0 = (u64)(iy0 * WG + ix0);
  const u64 o1 = (u64)(iy0 * WG + ix1);
  const u64 o2 = (u64)(iy1 * WG + ix0);
  const u64 o3 = (u64)(iy1 * WG + ix1);
  off8[pid] = o0 | (o1 << 16) | (o2 << 32) | (o3 << 48);
  w4[pid] = make_float4((vx0 && vy0) ? (1.f - wx) * (1.f - wy) : 0.f,
                        (vx1 && vy0) ? wx * (1.f - wy) : 0.f,
                        (vx0 && vy1) ? (1.f - wx) * wy : 0.f,
                        (vx1 && vy1) ? wx * wy : 0.f);
  pn4[pid] = make_float4(fminf(fmaxf((px + 50.f) * 0.01f, 0.f), 1.f),
                         fminf(fmaxf((py + 50.f) * 0.01f, 0.f), 1.f),
                         fminf(fmaxf((pz + 4.f) * 0.125f, 0.f), 1.f), 0.f);
}

// ---------------- kernel B: MLP via MFMA + bilinear gather + coalesced write ----------------
// R3-validated structure. ONLY change vs R3: bijective XCD chunk swizzle (T1/m204) on the
// block id so each XCD's blocks share a contiguous featT slice (~1.3 MB, fits 4 MB L2).
__global__ __launch_bounds__(256, 4) void gemm_k(
    const float* __restrict__ featT,  // (BN,L,C)
    const float* __restrict__ W1,
    const float* __restrict__ b1,
    const unsigned short* __restrict__ W2bf,
    const float* __restrict__ b2,
    const u64* __restrict__ off8,
    const float4* __restrict__ w4,
    const float4* __restrict__ pn4,
    float* __restrict__ out) {
  const int tid = threadIdx.x;

  // nwg=6300, q=787, r=4: xcd<4 get chunks of 788, xcd>=4 chunks of 787. Bijective.
  const int orig = blockIdx.x;
  const int xcd = orig & 7;
  const int pos = orig >> 3;
  const int wgid = (xcd < 4 ? xcd * 788 : 4 * 788 + (xcd - 4) * 787) + pos;
  if (wgid >= NWG) return;  // provably unreachable; loud-fail safety

  const int gp0 = wgid * NPB;
  const int bn = wgid / 525;  // 33600 points per bn / 64; blocks never span bn

  __shared__ __align__(16) char sH[NPB * 512];
  __shared__ u64 sOff8[NPB];
  __shared__ float4 sWl[NPB];
  __shared__ float4 sPnl[NPB];

  // stage per-point records (coalesced)
  if (tid < NPB) {
    sOff8[tid] = off8[gp0 + tid];
    sWl[tid] = w4[gp0 + tid];
    sPnl[tid] = pn4[gp0 + tid];
  }

  const int wv = tid >> 6;
  const int lane = tid & 63;
  const int lrow = lane & 15;
  const int g = lane >> 4;

  // B-fragments for this wave's 32 channels (issued early; latency hides under phase A)
  v8s fb0[8], fb1[8];
#pragma unroll
  for (int ks = 0; ks < 8; ++ks) {
    fb0[ks] = *(const v8s*)(W2bf + (size_t)(((wv * 2 + 0) * 8 + ks) * 64 + lane) * 8);
    fb1[ks] = *(const v8s*)(W2bf + (size_t)(((wv * 2 + 1) * 8 + ks) * 64 + lane) * 8);
  }

  // W1/b1 slice: loaded ONCE (h4 is loop-invariant per thread)
  const int h4 = (tid & 63) * 4;
  const int pw = tid >> 6;
  const float4 a0 = *(const float4*)(W1 + h4);
  const float4 a1 = *(const float4*)(W1 + HID + h4);
  const float4 a2 = *(const float4*)(W1 + 2 * HID + h4);
  const float4 bb = *(const float4*)(b1 + h4);

  __syncthreads();

  // phase A: H[64][256] = relu(pn @ W1 + b1) -> bf16 LDS (swizzled), b64 writes
#pragma unroll
  for (int it = 0; it < NPB / 4; ++it) {
    const int p = it * 4 + pw;
    const float4 pn = sPnl[p];
    const float v0 = fmaxf(bb.x + pn.x * a0.x + pn.y * a1.x + pn.z * a2.x, 0.f);
    const float v1 = fmaxf(bb.y + pn.x * a0.y + pn.y * a1.y + pn.z * a2.y, 0.f);
    const float v2 = fmaxf(bb.z + pn.x * a0.z + pn.y * a1.z + pn.z * a2.z, 0.f);
    const float v3 = fmaxf(bb.w + pn.x * a0.w + pn.y * a1.w + pn.z * a2.w, 0.f);
    const u64 pk = (u64)f2bf(v0) | ((u64)f2bf(v1) << 16) | ((u64)f2bf(v2) << 32) |
                   ((u64)f2bf(v3) << 48);
    *(u64*)(sH + p * 512 + (((unsigned)(h4 * 2)) ^ (((unsigned)(p & 7)) << 4))) = pk;
  }
  __syncthreads();

  // phase B: per 16-point tile: MFMA then in-place transpose into the same rows
  for (int pt = 0; pt < 4; ++pt) {
    const int arow = pt * 16 + lrow;
    const unsigned swz = ((unsigned)(arow & 7)) << 4;
    v8s fa[8];
#pragma unroll
    for (int ks = 0; ks < 8; ++ks)
      fa[ks] = *(const v8s*)(sH + arow * 512 + (((unsigned)(ks * 64 + g * 16)) ^ swz));
    v4f acc0 = {0.f, 0.f, 0.f, 0.f};
    v4f acc1 = {0.f, 0.f, 0.f, 0.f};
#pragma unroll
    for (int ks = 0; ks < 8; ++ks)
      acc0 = __builtin_amdgcn_mfma_f32_16x16x32_bf16(fa[ks], fb0[ks], acc0, 0, 0, 0);
#pragma unroll
    for (int ks = 0; ks < 8; ++ks)
      acc1 = __builtin_amdgcn_mfma_f32_16x16x32_bf16(fa[ks], fb1[ks], acc1, 0, 0, 0);
    __syncthreads();  // all waves done reading H rows of this tile
#pragma unroll
    for (int r = 0; r < 4; ++r) {
      const int lp = pt * 16 + g * 4 + r;  // C/D: row=(lane>>4)*4+r, col=lane&15
      const unsigned s2 = ((unsigned)(lp & 7)) << 4;
      const int c0 = wv * 32 + lrow;
      *(float*)(sH + lp * 512 + (((unsigned)(c0 * 4)) ^ s2)) = acc0[r];
      *(float*)(sH + lp * 512 + (((unsigned)((c0 + 16) * 4)) ^ s2)) = acc1[r];
    }
    __syncthreads();  // writes visible before next tile / epilogue
  }

  // epilogue: bias + bilinear gather + fully-coalesced float4 stores
  const float* featc = featT + (size_t)bn * (LL * CC);
#pragma unroll
  for (int it = 0; it < 8; ++it) {
    const int p = it * 8 + (tid >> 5);
    const int c4g = tid & 31;
    const unsigned boff =
        (unsigned)(p * 512) + (((unsigned)(c4g * 16)) ^ (((unsigned)(p & 7)) << 4));
    const v4f t = *(const v4f*)(sH + boff);
    const u64 o8 = sOff8[p];
    const float4 w = sWl[p];
    const float4 bias = *(const float4*)(b2 + c4g * 4);
    float rx = t[0] + bias.x, ry = t[1] + bias.y, rz = t[2] + bias.z, rw = t[3] + bias.w;
    {
      const float4 f = *(const float4*)(featc + (size_t)(unsigned)(o8 & 0xFFFFu) * CC + c4g * 4);
      rx += w.x * f.x; ry += w.x * f.y; rz += w.x * f.z; rw += w.x * f.w;
    }
    {
      const float4 f =
          *(const float4*)(featc + (size_t)(unsigned)((o8 >> 16) & 0xFFFFu) * CC + c4g * 4);
      rx += w.y * f.x; ry += w.y * f.y; rz += w.y * f.z; rw += w.y * f.w;
    }
    {
      const float4 f =
          *(const float4*)(featc + (size_t)(unsigned)((o8 >> 32) & 0xFFFFu) * CC + c4g * 4);
      rx += w.z * f.x; ry += w.z * f.y; rz += w.z * f.z; rw += w.z * f.w;
    }
    {
      const float4 f =
          *(const float4*)(featc + (size_t)(unsigned)((o8 >> 48) & 0xFFFFu) * CC + c4g * 4);
      rx += w.w * f.x; ry += w.w * f.y; rz += w.w * f.z; rw += w.w * f.w;
    }
    *(float4*)(out + (size_t)(gp0 + p) * CC + c4g * 4) = make_float4(rx, ry, rz, rw);
  }
}

// ---------------- last-resort fallback (no ws): fused fp32 kernel ----------------
__global__ __launch_bounds__(128) void gauss_fb(
    const float* __restrict__ means3D, const float* __restrict__ feat,
    const float* __restrict__ dvec, const float* __restrict__ cov3D,
    const float* __restrict__ l2i, const float* __restrict__ W1,
    const float* __restrict__ b1, const float* __restrict__ W2,
    const float* __restrict__ b2, float* __restrict__ out) {
  const int l = blockIdx.x;
  const int bn = blockIdx.y;
  const int tid = threadIdx.x;
  __shared__ float sH[P2][HID];
  __shared__ float sPn[P2][3];
  __shared__ float sW[P2][4];
  __shared__ int sOff[P2][4];
  if (tid < P2) {
    const int p = tid;
    const size_t base3 = ((size_t)bn * LL + l) * 3;
    const float m0 = means3D[base3 + 0], m1 = means3D[base3 + 1], m2 = means3D[base3 + 2];
    const float d0 = dvec[base3 + 0], d1 = dvec[base3 + 1], d2 = dvec[base3 + 2];
    const float* cv = cov3D + ((size_t)bn * LL + l) * 9;
    const float q = d0 * (cv[0] * d0 + cv[1] * d1 + cv[2] * d2) +
                    d1 * (cv[3] * d0 + cv[4] * d1 + cv[5] * d2) +
                    d2 * (cv[6] * d0 + cv[7] * d1 + cv[8] * d2);
    const float s = sqrtf(q);
    const int k = p >> 2, j = p & 3;
    const float a = (-1.5f + 0.75f * (float)k) * s;
    const float tt = -0.5f + (1.0f / 3.0f) * (float)j;
    const float px = m0 + a * d0 + tt * d1;
    const float py = m1 + a * d1 - tt * d0;
    const float pz = m2 + a * d2;
    const float* M = l2i + (size_t)bn * 16;
    const float cx = M[0] * px + M[1] * py + M[2] * pz + M[3];
    const float cy = M[4] * px + M[5] * py + M[6] * pz + M[7];
    const float cz = M[8] * px + M[9] * py + M[10] * pz + M[11];
    const float homo = fmaxf(cz, 1e-6f);
    const float u = cx / homo;
    const float v = cy / homo;
    float* camo = out + OUT_CAM_OFF + (((size_t)bn * LL + l) * P2 + p) * 2;
    camo[0] = u;
    camo[1] = v;
    float* ptso = out + OUT_PTS_OFF + (((size_t)bn * LL + l) * P2 + p) * 3;
    ptso[0] = px;
    ptso[1] = py;
    ptso[2] = pz;
    const float x = u * 0.125f - 0.5f;
    const float y = v * 0.125f - 0.5f;
    const float x0f = floorf(x), y0f = floorf(y);
    const float wx = x - x0f, wy = y - y0f;
    const bool vx0 = (x0f >= 0.f) && (x0f < (float)WG);
    const bool vx1 = (x0f + 1.f >= 0.f) && (x0f + 1.f < (float)WG);
    const bool vy0 = (y0f >= 0.f) && (y0f < (float)HG);
    const bool vy1 = (y0f + 1.f >= 0.f) && (y0f + 1.f < (float)HG);
    const int ix0 = (int)fminf(fmaxf(x0f, 0.f), (float)(WG - 1));
    const int ix1 = (int)fminf(fmaxf(x0f + 1.f, 0.f), (float)(WG - 1));
    const int iy0 = (int)fminf(fmaxf(y0f, 0.f), (float)(HG - 1));
    const int iy1 = (int)fminf(fmaxf(y0f + 1.f, 0.f), (float)(HG - 1));
    sOff[p][0] = iy0 * WG + ix0;
    sOff[p][1] = iy0 * WG + ix1;
    sOff[p][2] = iy1 * WG + ix0;
    sOff[p][3] = iy1 * WG + ix1;
    sW[p][0] = (vx0 && vy0) ? (1.f - wx) * (1.f - wy) : 0.f;
    sW[p][1] = (vx1 && vy0) ? wx * (1.f - wy) : 0.f;
    sW[p][2] = (vx0 && vy1) ? (1.f - wx) * wy : 0.f;
    sW[p][3] = (vx1 && vy1) ? wx * wy : 0.f;
    sPn[p][0] = fminf(fmaxf((px + 50.f) * 0.01f, 0.f), 1.f);
    sPn[p][1] = fminf(fmaxf((py + 50.f) * 0.01f, 0.f), 1.f);
    sPn[p][2] = fminf(fmaxf((pz + 4.f) * 0.125f, 0.f), 1.f);
  }
  __syncthreads();
  for (int u0 = tid; u0 < P2 * HID; u0 += 128) {
    const int p = u0 >> 8;
    const int h = u0 & (HID - 1);
    const float v = b1[h] + sPn[p][0] * W1[h] + sPn[p][1] * W1[HID + h] + sPn[p][2] * W1[2 * HID + h];
    sH[p][h] = fmaxf(v, 0.f);
  }
  __syncthreads();
  const int pg = tid >> 5;
  const int c0 = (tid & 31) * 4;
  const int pbase = pg * 5;
  float acc[5][4];
#pragma unroll
  for (int i = 0; i < 5; ++i)
#pragma unroll
    for (int j2 = 0; j2 < 4; ++j2) acc[i][j2] = 0.f;
  for (int h = 0; h < HID; h += 4) {
    const float4 w0 = *(const float4*)(W2 + (size_t)(h + 0) * CC + c0);
    const float4 w1 = *(const float4*)(W2 + (size_t)(h + 1) * CC + c0);
    const float4 w2 = *(const float4*)(W2 + (size_t)(h + 2) * CC + c0);
    const float4 w3 = *(const float4*)(W2 + (size_t)(h + 3) * CC + c0);
#pragma unroll
    for (int i = 0; i < 5; ++i) {
      const float4 hv = *(const float4*)(&sH[pbase + i][h]);
      acc[i][0] += hv.x * w0.x + hv.y * w1.x + hv.z * w2.x + hv.w * w3.x;
      acc[i][1] += hv.x * w0.y + hv.y * w1.y + hv.z * w2.y + hv.w * w3.y;
      acc[i][2] += hv.x * w0.z + hv.y * w1.z + hv.z * w2.z + hv.w * w3.z;
      acc[i][3] += hv.x * w0.w + hv.y * w1.w + hv.z * w2.w + hv.w * w3.w;
    }
  }
  const float4 bias = *(const float4*)(b2 + c0);
  const float* fbase = feat + (size_t)bn * CC * LL;
#pragma unroll
  for (int i = 0; i < 5; ++i) {
    const int p = pbase + i;
    float4 r;
    r.x = acc[i][0] + bias.x;
    r.y = acc[i][1] + bias.y;
    r.z = acc[i][2] + bias.z;
    r.w = acc[i][3] + bias.w;
#pragma unroll
    for (int corner = 0; corner < 4; ++corner) {
      const float w = sW[p][corner];
      const int off = sOff[p][corner];
      r.x += w * fbase[(size_t)(c0 + 0) * LL + off];
      r.y += w * fbase[(size_t)(c0 + 1) * LL + off];
      r.z += w * fbase[(size_t)(c0 + 2) * LL + off];
      r.w += w * fbase[(size_t)(c0 + 3) * LL + off];
    }
    *(float4*)(out + (((size_t)bn * LL + l) * P2 + p) * CC + c0) = r;
  }
}

extern "C" void kernel_launch(void* const* d_in, const int* in_sizes, int n_in,
                              void* d_out, int out_size, void* d_ws, size_t ws_size,
                              hipStream_t stream) {
  const float* means3D = (const float*)d_in[0];
  const float* img = (const float*)d_in[1];
  const float* dvec = (const float*)d_in[2];
  const float* cov3D = (const float*)d_in[3];
  const float* l2i = (const float*)d_in[4];
  const float* W1 = (const float*)d_in[5];
  const float* b1 = (const float*)d_in[6];
  const float* W2 = (const float*)d_in[7];
  const float* b2 = (const float*)d_in[8];
  float* out = (float*)d_out;

  const size_t w2bf_bytes = 65536;
  const size_t tbytes = (size_t)BN * LL * CC * sizeof(float);  // 10321920
  const size_t off8_bytes = (size_t)NPTS * 8;                  // 3225600
  const size_t w4_bytes = (size_t)NPTS * 16;                   // 6451200
  const size_t need_full = w2bf_bytes + tbytes + off8_bytes + 2 * w4_bytes;  // 26515456

  if (ws_size >= need_full) {
    unsigned short* W2bf = (unsigned short*)d_ws;
    float* featT = (float*)((char*)d_ws + w2bf_bytes);
    u64* off8 = (u64*)((char*)d_ws + w2bf_bytes + tbytes);
    float4* w4 = (float4*)((char*)d_ws + w2bf_bytes + tbytes + off8_bytes);
    float4* pn4 = (float4*)((char*)d_ws + w2bf_bytes + tbytes + off8_bytes + w4_bytes);
    hipLaunchKernelGGL(pack_w2_k, dim3(16), dim3(256), 0, stream, W2, W2bf);
    hipLaunchKernelGGL(transpose_feat_k, dim3((LL + 63) / 64, CC / 64, BN), dim3(256), 0,
                       stream, img, featT);
    hipLaunchKernelGGL(geom_k, dim3(NPTS / 256), dim3(256), 0, stream, means3D, dvec, cov3D,
                       l2i, out, off8, w4, pn4);
    hipLaunchKernelGGL(gemm_k, dim3(NWG), dim3(256), 0, stream, featT, W1, b1, W2bf, b2,
                       off8, w4, pn4, out);
  } else {
    hipLaunchKernelGGL(gauss_fb, dim3(LL, BN), dim3(128), 0, stream, means3D, img, dvec, cov3D,
                       l2i, W1, b1, W2, b2, out);
  }
}

// Round 6
// 98.058 us; speedup vs baseline: 1.0196x; 1.0196x over previous
//
#include <hip/hip_runtime.h>
#include <hip/hip_bf16.h>
#include <math.h>

#define BN 12
#define HG 28
#define WG 60
#define LL 1680      // HG*WG
#define CC 128
#define P2 20
#define HID 256
#define NPTS (BN * LL * P2)  // 403200
#define NPB 64               // points per block in gemm kernel
#define NWG (NPTS / NPB)     // 6300

static constexpr size_t OUT_CAM_OFF = (size_t)BN * LL * P2 * CC;              // 51609600
static constexpr size_t OUT_PTS_OFF = OUT_CAM_OFF + (size_t)BN * LL * P2 * 2; // 52416000

typedef short v8s __attribute__((ext_vector_type(8)));
typedef float v4f __attribute__((ext_vector_type(4)));
typedef unsigned long long u64;

__device__ __forceinline__ unsigned short f2bf(float f) {
  unsigned x = __float_as_uint(f);
  unsigned r = (x + 0x7FFFu + ((x >> 16) & 1u)) >> 16;
  return (unsigned short)r;
}

// ---------------- transpose img_features (BN,C,L) -> (BN,L,C) ----------------
__global__ __launch_bounds__(256) void transpose_feat_k(const float* __restrict__ in,
                                                        float* __restrict__ out) {
  __shared__ float tile[64][65];
  const int bn = blockIdx.z;
  const int c0 = blockIdx.y * 64;
  const int l0 = blockIdx.x * 64;
  const int t = threadIdx.x;
  {
    const int lx = t & 63;
    const int cy = t >> 6;
#pragma unroll
    for (int i = 0; i < 64; i += 4) {
      const int c = c0 + cy + i;
      const int l = l0 + lx;
      float v = 0.f;
      if (l < LL) v = in[((size_t)bn * CC + c) * LL + l];
      tile[cy + i][lx] = v;
    }
  }
  __syncthreads();
  {
    const int cx = t & 63;
    const int ly = t >> 6;
#pragma unroll
    for (int i = 0; i < 64; i += 4) {
      const int l = l0 + ly + i;
      const int c = c0 + cx;
      if (l < LL) out[((size_t)bn * LL + l) * CC + c] = tile[cx][ly + i];
    }
  }
}

// ---------------- pack W2 (256x128 f32) into bf16 B-fragment order ----------------
__global__ __launch_bounds__(256) void pack_w2_k(const float* __restrict__ W2,
                                                 unsigned short* __restrict__ W2bf) {
  const int t = blockIdx.x * 256 + threadIdx.x;
  if (t >= 4096) return;
  const int lane = t & 63;
  const int ks = (t >> 6) & 7;
  const int cg = t >> 9;
  const int col = cg * 16 + (lane & 15);
  const int kb = ks * 32 + (lane >> 4) * 8;
  v8s r;
#pragma unroll
  for (int e = 0; e < 8; ++e) r[e] = (short)f2bf(W2[(size_t)(kb + e) * CC + col]);
  *(v8s*)(W2bf + (size_t)t * 8) = r;
}

// ---------------- kernel A: geometry, cam/pts outputs, per-point records ----------------
// FROZEN since R3 (passing twice). cam = cx/homo amplifies contraction-order noise near the
// homo clamp ~1e6x; do not re-compile this math in a different kernel context.
__global__ __launch_bounds__(256) void geom_k(const float* __restrict__ means3D,
                                              const float* __restrict__ dvec,
                                              const float* __restrict__ cov3D,
                                              const float* __restrict__ l2i,
                                              float* __restrict__ out,
                                              u64* __restrict__ off8,
                                              float4* __restrict__ w4,
                                              float4* __restrict__ pn4) {
  const int pid = blockIdx.x * 256 + threadIdx.x;
  if (pid >= NPTS) return;
  const unsigned qg = (unsigned)pid / P2;
  const int p = pid - (int)qg * P2;
  const unsigned bn = qg / LL;

  const size_t base3 = (size_t)qg * 3;
  const float m0 = means3D[base3 + 0], m1 = means3D[base3 + 1], m2 = means3D[base3 + 2];
  const float d0 = dvec[base3 + 0], d1 = dvec[base3 + 1], d2 = dvec[base3 + 2];
  const float* cv = cov3D + (size_t)qg * 9;
  const float q = d0 * (cv[0] * d0 + cv[1] * d1 + cv[2] * d2) +
                  d1 * (cv[3] * d0 + cv[4] * d1 + cv[5] * d2) +
                  d2 * (cv[6] * d0 + cv[7] * d1 + cv[8] * d2);
  const float s = sqrtf(q);
  const int k = p >> 2, j = p & 3;
  const float a = (-1.5f + 0.75f * (float)k) * s;     // lin5[k]*sqrt(q)
  const float tt = -0.5f + (1.0f / 3.0f) * (float)j;  // linP[j]
  const float px = m0 + a * d0 + tt * d1;
  const float py = m1 + a * d1 - tt * d0;
  const float pz = m2 + a * d2;
  const float* M = l2i + (size_t)bn * 16;
  const float cx = M[0] * px + M[1] * py + M[2] * pz + M[3];
  const float cy = M[4] * px + M[5] * py + M[6] * pz + M[7];
  const float cz = M[8] * px + M[9] * py + M[10] * pz + M[11];
  const float homo = fmaxf(cz, 1e-6f);
  const float u = cx / homo;
  const float v = cy / homo;

  *(float2*)(out + OUT_CAM_OFF + (size_t)pid * 2) = make_float2(u, v);
  float* ptso = out + OUT_PTS_OFF + (size_t)pid * 3;
  ptso[0] = px;
  ptso[1] = py;
  ptso[2] = pz;

  const float x = u * 0.125f - 0.5f;
  const float y = v * 0.125f - 0.5f;
  const float x0f = floorf(x), y0f = floorf(y);
  const float wx = x - x0f, wy = y - y0f;
  const bool vx0 = (x0f >= 0.f) && (x0f < (float)WG);
  const bool vx1 = (x0f + 1.f >= 0.f) && (x0f + 1.f < (float)WG);
  const bool vy0 = (y0f >= 0.f) && (y0f < (float)HG);
  const bool vy1 = (y0f + 1.f >= 0.f) && (y0f + 1.f < (float)HG);
  const unsigned ix0 = (unsigned)(int)fminf(fmaxf(x0f, 0.f), (float)(WG - 1));
  const unsigned ix1 = (unsigned)(int)fminf(fmaxf(x0f + 1.f, 0.f), (float)(WG - 1));
  const unsigned iy0 = (unsigned)(int)fminf(fmaxf(y0f, 0.f), (float)(HG - 1));
  const unsigned iy1 = (unsigned)(int)fminf(fmaxf(y0f + 1.f, 0.f), (float)(HG - 1));
  const u64 o0 = (u64)(iy0 * WG + ix0);
  const u64 o1 = (u64)(iy0 * WG + ix1);
  const u64 o2 = (u64)(iy1 * WG + ix0);
  const u64 o3 = (u64)(iy1 * WG + ix1);
  off8[pid] = o0 | (o1 << 16) | (o2 << 32) | (o3 << 48);
  w4[pid] = make_float4((vx0 && vy0) ? (1.f - wx) * (1.f - wy) : 0.f,
                        (vx1 && vy0) ? wx * (1.f - wy) : 0.f,
                        (vx0 && vy1) ? (1.f - wx) * wy : 0.f,
                        (vx1 && vy1) ? wx * wy : 0.f);
  pn4[pid] = make_float4(fminf(fmaxf((px + 50.f) * 0.01f, 0.f), 1.f),
                         fminf(fmaxf((py + 50.f) * 0.01f, 0.f), 1.f),
                         fminf(fmaxf((pz + 4.f) * 0.125f, 0.f), 1.f), 0.f);
}

// ---------------- kernel B: MLP via MFMA + bilinear gather + coalesced write ----------------
// R6 edits vs validated R5: (1) no block swizzle (R5 measured neutral); (2) tile PAIRS:
// MFMA both tiles -> 1 barrier -> transpose both -> 1 barrier (10 -> 6 barriers total);
// (3) phase-A bf16 pack via v_cvt_pk (RNE, bit-identical to f2bf). Math order unchanged.
__global__ __launch_bounds__(256, 4) void gemm_k(
    const float* __restrict__ featT,  // (BN,L,C)
    const float* __restrict__ W1,
    const float* __restrict__ b1,
    const unsigned short* __restrict__ W2bf,
    const float* __restrict__ b2,
    const u64* __restrict__ off8,
    const float4* __restrict__ w4,
    const float4* __restrict__ pn4,
    float* __restrict__ out) {
  const int tid = threadIdx.x;
  const int wgid = blockIdx.x;
  const int gp0 = wgid * NPB;
  const int bn = wgid / 525;  // 33600 points per bn / 64; blocks never span bn

  __shared__ __align__(16) char sH[NPB * 512];
  __shared__ u64 sOff8[NPB];
  __shared__ float4 sWl[NPB];
  __shared__ float4 sPnl[NPB];

  // stage per-point records (coalesced)
  if (tid < NPB) {
    sOff8[tid] = off8[gp0 + tid];
    sWl[tid] = w4[gp0 + tid];
    sPnl[tid] = pn4[gp0 + tid];
  }

  const int wv = tid >> 6;
  const int lane = tid & 63;
  const int lrow = lane & 15;
  const int g = lane >> 4;

  // B-fragments for this wave's 32 channels (issued early; latency hides under phase A)
  v8s fb0[8], fb1[8];
#pragma unroll
  for (int ks = 0; ks < 8; ++ks) {
    fb0[ks] = *(const v8s*)(W2bf + (size_t)(((wv * 2 + 0) * 8 + ks) * 64 + lane) * 8);
    fb1[ks] = *(const v8s*)(W2bf + (size_t)(((wv * 2 + 1) * 8 + ks) * 64 + lane) * 8);
  }

  // W1/b1 slice: loaded ONCE (h4 is loop-invariant per thread)
  const int h4 = (tid & 63) * 4;
  const int pw = tid >> 6;
  const float4 a0 = *(const float4*)(W1 + h4);
  const float4 a1 = *(const float4*)(W1 + HID + h4);
  const float4 a2 = *(const float4*)(W1 + 2 * HID + h4);
  const float4 bb = *(const float4*)(b1 + h4);

  __syncthreads();

  // phase A: H[64][256] = relu(pn @ W1 + b1) -> bf16 LDS (swizzled), b64 writes
#pragma unroll
  for (int it = 0; it < NPB / 4; ++it) {
    const int p = it * 4 + pw;
    const float4 pn = sPnl[p];
    const float v0 = fmaxf(bb.x + pn.x * a0.x + pn.y * a1.x + pn.z * a2.x, 0.f);
    const float v1 = fmaxf(bb.y + pn.x * a0.y + pn.y * a1.y + pn.z * a2.y, 0.f);
    const float v2 = fmaxf(bb.z + pn.x * a0.z + pn.y * a1.z + pn.z * a2.z, 0.f);
    const float v3 = fmaxf(bb.w + pn.x * a0.w + pn.y * a1.w + pn.z * a2.w, 0.f);
    __hip_bfloat162 plo = __float22bfloat162_rn(make_float2(v0, v1));
    __hip_bfloat162 phi = __float22bfloat162_rn(make_float2(v2, v3));
    const unsigned ulo = *reinterpret_cast<const unsigned*>(&plo);
    const unsigned uhi = *reinterpret_cast<const unsigned*>(&phi);
    const u64 pk = (u64)ulo | ((u64)uhi << 32);
    *(u64*)(sH + p * 512 + (((unsigned)(h4 * 2)) ^ (((unsigned)(p & 7)) << 4))) = pk;
  }
  __syncthreads();

  // phase B: tile pairs {0,1},{2,3}: MFMA both -> barrier -> transpose both -> barrier
#pragma unroll
  for (int pg2 = 0; pg2 < 2; ++pg2) {
    v4f acc[2][2];
#pragma unroll
    for (int i = 0; i < 2; ++i)
#pragma unroll
      for (int c = 0; c < 2; ++c) acc[i][c] = (v4f){0.f, 0.f, 0.f, 0.f};

#pragma unroll
    for (int pth = 0; pth < 2; ++pth) {
      const int pt = pg2 * 2 + pth;
      const int arow = pt * 16 + lrow;
      const unsigned swz = ((unsigned)(arow & 7)) << 4;
      v8s fa[8];
#pragma unroll
      for (int ks = 0; ks < 8; ++ks)
        fa[ks] = *(const v8s*)(sH + arow * 512 + (((unsigned)(ks * 64 + g * 16)) ^ swz));
#pragma unroll
      for (int ks = 0; ks < 8; ++ks)
        acc[pth][0] = __builtin_amdgcn_mfma_f32_16x16x32_bf16(fa[ks], fb0[ks], acc[pth][0], 0, 0, 0);
#pragma unroll
      for (int ks = 0; ks < 8; ++ks)
        acc[pth][1] = __builtin_amdgcn_mfma_f32_16x16x32_bf16(fa[ks], fb1[ks], acc[pth][1], 0, 0, 0);
    }
    __syncthreads();  // all waves done reading rows of this tile pair
#pragma unroll
    for (int pth = 0; pth < 2; ++pth) {
      const int pt = pg2 * 2 + pth;
#pragma unroll
      for (int r = 0; r < 4; ++r) {
        const int lp = pt * 16 + g * 4 + r;  // C/D: row=(lane>>4)*4+r, col=lane&15
        const unsigned s2 = ((unsigned)(lp & 7)) << 4;
        const int c0 = wv * 32 + lrow;
        *(float*)(sH + lp * 512 + (((unsigned)(c0 * 4)) ^ s2)) = acc[pth][0][r];
        *(float*)(sH + lp * 512 + (((unsigned)((c0 + 16) * 4)) ^ s2)) = acc[pth][1][r];
      }
    }
    __syncthreads();  // writes visible before next pair / epilogue
  }

  // epilogue: bias + bilinear gather + fully-coalesced float4 stores
  const float* featc = featT + (size_t)bn * (LL * CC);
#pragma unroll
  for (int it = 0; it < 8; ++it) {
    const int p = it * 8 + (tid >> 5);
    const int c4g = tid & 31;
    const unsigned boff =
        (unsigned)(p * 512) + (((unsigned)(c4g * 16)) ^ (((unsigned)(p & 7)) << 4));
    const v4f t = *(const v4f*)(sH + boff);
    const u64 o8 = sOff8[p];
    const float4 w = sWl[p];
    const float4 bias = *(const float4*)(b2 + c4g * 4);
    float rx = t[0] + bias.x, ry = t[1] + bias.y, rz = t[2] + bias.z, rw = t[3] + bias.w;
    {
      const float4 f = *(const float4*)(featc + (size_t)(unsigned)(o8 & 0xFFFFu) * CC + c4g * 4);
      rx += w.x * f.x; ry += w.x * f.y; rz += w.x * f.z; rw += w.x * f.w;
    }
    {
      const float4 f =
          *(const float4*)(featc + (size_t)(unsigned)((o8 >> 16) & 0xFFFFu) * CC + c4g * 4);
      rx += w.y * f.x; ry += w.y * f.y; rz += w.y * f.z; rw += w.y * f.w;
    }
    {
      const float4 f =
          *(const float4*)(featc + (size_t)(unsigned)((o8 >> 32) & 0xFFFFu) * CC + c4g * 4);
      rx += w.z * f.x; ry += w.z * f.y; rz += w.z * f.z; rw += w.z * f.w;
    }
    {
      const float4 f =
          *(const float4*)(featc + (size_t)(unsigned)((o8 >> 48) & 0xFFFFu) * CC + c4g * 4);
      rx += w.w * f.x; ry += w.w * f.y; rz += w.w * f.z; rw += w.w * f.w;
    }
    *(float4*)(out + (size_t)(gp0 + p) * CC + c4g * 4) = make_float4(rx, ry, rz, rw);
  }
}

// ---------------- last-resort fallback (no ws): fused fp32 kernel ----------------
__global__ __launch_bounds__(128) void gauss_fb(
    const float* __restrict__ means3D, const float* __restrict__ feat,
    const float* __restrict__ dvec, const float* __restrict__ cov3D,
    const float* __restrict__ l2i, const float* __restrict__ W1,
    const float* __restrict__ b1, const float* __restrict__ W2,
    const float* __restrict__ b2, float* __restrict__ out) {
  const int l = blockIdx.x;
  const int bn = blockIdx.y;
  const int tid = threadIdx.x;
  __shared__ float sH[P2][HID];
  __shared__ float sPn[P2][3];
  __shared__ float sW[P2][4];
  __shared__ int sOff[P2][4];
  if (tid < P2) {
    const int p = tid;
    const size_t base3 = ((size_t)bn * LL + l) * 3;
    const float m0 = means3D[base3 + 0], m1 = means3D[base3 + 1], m2 = means3D[base3 + 2];
    const float d0 = dvec[base3 + 0], d1 = dvec[base3 + 1], d2 = dvec[base3 + 2];
    const float* cv = cov3D + ((size_t)bn * LL + l) * 9;
    const float q = d0 * (cv[0] * d0 + cv[1] * d1 + cv[2] * d2) +
                    d1 * (cv[3] * d0 + cv[4] * d1 + cv[5] * d2) +
                    d2 * (cv[6] * d0 + cv[7] * d1 + cv[8] * d2);
    const float s = sqrtf(q);
    const int k = p >> 2, j = p & 3;
    const float a = (-1.5f + 0.75f * (float)k) * s;
    const float tt = -0.5f + (1.0f / 3.0f) * (float)j;
    const float px = m0 + a * d0 + tt * d1;
    const float py = m1 + a * d1 - tt * d0;
    const float pz = m2 + a * d2;
    const float* M = l2i + (size_t)bn * 16;
    const float cx = M[0] * px + M[1] * py + M[2] * pz + M[3];
    const float cy = M[4] * px + M[5] * py + M[6] * pz + M[7];
    const float cz = M[8] * px + M[9] * py + M[10] * pz + M[11];
    const float homo = fmaxf(cz, 1e-6f);
    const float u = cx / homo;
    const float v = cy / homo;
    float* camo = out + OUT_CAM_OFF + (((size_t)bn * LL + l) * P2 + p) * 2;
    camo[0] = u;
    camo[1] = v;
    float* ptso = out + OUT_PTS_OFF + (((size_t)bn * LL + l) * P2 + p) * 3;
    ptso[0] = px;
    ptso[1] = py;
    ptso[2] = pz;
    const float x = u * 0.125f - 0.5f;
    const float y = v * 0.125f - 0.5f;
    const float x0f = floorf(x), y0f = floorf(y);
    const float wx = x - x0f, wy = y - y0f;
    const bool vx0 = (x0f >= 0.f) && (x0f < (float)WG);
    const bool vx1 = (x0f + 1.f >= 0.f) && (x0f + 1.f < (float)WG);
    const bool vy0 = (y0f >= 0.f) && (y0f < (float)HG);
    const bool vy1 = (y0f + 1.f >= 0.f) && (y0f + 1.f < (float)HG);
    const int ix0 = (int)fminf(fmaxf(x0f, 0.f), (float)(WG - 1));
    const int ix1 = (int)fminf(fmaxf(x0f + 1.f, 0.f), (float)(WG - 1));
    const int iy0 = (int)fminf(fmaxf(y0f, 0.f), (float)(HG - 1));
    const int iy1 = (int)fminf(fmaxf(y0f + 1.f, 0.f), (float)(HG - 1));
    sOff[p][0] = iy0 * WG + ix0;
    sOff[p][1] = iy0 * WG + ix1;
    sOff[p][2] = iy1 * WG + ix0;
    sOff[p][3] = iy1 * WG + ix1;
    sW[p][0] = (vx0 && vy0) ? (1.f - wx) * (1.f - wy) : 0.f;
    sW[p][1] = (vx1 && vy0) ? wx * (1.f - wy) : 0.f;
    sW[p][2] = (vx0 && vy1) ? (1.f - wx) * wy : 0.f;
    sW[p][3] = (vx1 && vy1) ? wx * wy : 0.f;
    sPn[p][0] = fminf(fmaxf((px + 50.f) * 0.01f, 0.f), 1.f);
    sPn[p][1] = fminf(fmaxf((py + 50.f) * 0.01f, 0.f), 1.f);
    sPn[p][2] = fminf(fmaxf((pz + 4.f) * 0.125f, 0.f), 1.f);
  }
  __syncthreads();
  for (int u0 = tid; u0 < P2 * HID; u0 += 128) {
    const int p = u0 >> 8;
    const int h = u0 & (HID - 1);
    const float v = b1[h] + sPn[p][0] * W1[h] + sPn[p][1] * W1[HID + h] + sPn[p][2] * W1[2 * HID + h];
    sH[p][h] = fmaxf(v, 0.f);
  }
  __syncthreads();
  const int pg = tid >> 5;
  const int c0 = (tid & 31) * 4;
  const int pbase = pg * 5;
  float acc[5][4];
#pragma unroll
  for (int i = 0; i < 5; ++i)
#pragma unroll
    for (int j2 = 0; j2 < 4; ++j2) acc[i][j2] = 0.f;
  for (int h = 0; h < HID; h += 4) {
    const float4 w0 = *(const float4*)(W2 + (size_t)(h + 0) * CC + c0);
    const float4 w1 = *(const float4*)(W2 + (size_t)(h + 1) * CC + c0);
    const float4 w2 = *(const float4*)(W2 + (size_t)(h + 2) * CC + c0);
    const float4 w3 = *(const float4*)(W2 + (size_t)(h + 3) * CC + c0);
#pragma unroll
    for (int i = 0; i < 5; ++i) {
      const float4 hv = *(const float4*)(&sH[pbase + i][h]);
      acc[i][0] += hv.x * w0.x + hv.y * w1.x + hv.z * w2.x + hv.w * w3.x;
      acc[i][1] += hv.x * w0.y + hv.y * w1.y + hv.z * w2.y + hv.w * w3.y;
      acc[i][2] += hv.x * w0.z + hv.y * w1.z + hv.z * w2.z + hv.w * w3.z;
      acc[i][3] += hv.x * w0.w + hv.y * w1.w + hv.z * w2.w + hv.w * w3.w;
    }
  }
  const float4 bias = *(const float4*)(b2 + c0);
  const float* fbase = feat + (size_t)bn * CC * LL;
#pragma unroll
  for (int i = 0; i < 5; ++i) {
    const int p = pbase + i;
    float4 r;
    r.x = acc[i][0] + bias.x;
    r.y = acc[i][1] + bias.y;
    r.z = acc[i][2] + bias.z;
    r.w = acc[i][3] + bias.w;
#pragma unroll
    for (int corner = 0; corner < 4; ++corner) {
      const float w = sW[p][corner];
      const int off = sOff[p][corner];
      r.x += w * fbase[(size_t)(c0 + 0) * LL + off];
      r.y += w * fbase[(size_t)(c0 + 1) * LL + off];
      r.z += w * fbase[(size_t)(c0 + 2) * LL + off];
      r.w += w * fbase[(size_t)(c0 + 3) * LL + off];
    }
    *(float4*)(out + (((size_t)bn * LL + l) * P2 + p) * CC + c0) = r;
  }
}

extern "C" void kernel_launch(void* const* d_in, const int* in_sizes, int n_in,
                              void* d_out, int out_size, void* d_ws, size_t ws_size,
                              hipStream_t stream) {
  const float* means3D = (const float*)d_in[0];
  const float* img = (const float*)d_in[1];
  const float* dvec = (const float*)d_in[2];
  const float* cov3D = (const float*)d_in[3];
  const float* l2i = (const float*)d_in[4];
  const float* W1 = (const float*)d_in[5];
  const float* b1 = (const float*)d_in[6];
  const float* W2 = (const float*)d_in[7];
  const float* b2 = (const float*)d_in[8];
  float* out = (float*)d_out;

  const size_t w2bf_bytes = 65536;
  const size_t tbytes = (size_t)BN * LL * CC * sizeof(float);  // 10321920
  const size_t off8_bytes = (size_t)NPTS * 8;                  // 3225600
  const size_t w4_bytes = (size_t)NPTS * 16;                   // 6451200
  const size_t need_full = w2bf_bytes + tbytes + off8_bytes + 2 * w4_bytes;  // 26515456

  if (ws_size >= need_full) {
    unsigned short* W2bf = (unsigned short*)d_ws;
    float* featT = (float*)((char*)d_ws + w2bf_bytes);
    u64* off8 = (u64*)((char*)d_ws + w2bf_bytes + tbytes);
    float4* w4 = (float4*)((char*)d_ws + w2bf_bytes + tbytes + off8_bytes);
    float4* pn4 = (float4*)((char*)d_ws + w2bf_bytes + tbytes + off8_bytes + w4_bytes);
    hipLaunchKernelGGL(pack_w2_k, dim3(16), dim3(256), 0, stream, W2, W2bf);
    hipLaunchKernelGGL(transpose_feat_k, dim3((LL + 63) / 64, CC / 64, BN), dim3(256), 0,
                       stream, img, featT);
    hipLaunchKernelGGL(geom_k, dim3(NPTS / 256), dim3(256), 0, stream, means3D, dvec, cov3D,
                       l2i, out, off8, w4, pn4);
    hipLaunchKernelGGL(gemm_k, dim3(NWG), dim3(256), 0, stream, featT, W1, b1, W2bf, b2,
                       off8, w4, pn4, out);
  } else {
    hipLaunchKernelGGL(gauss_fb, dim3(LL, BN), dim3(128), 0, stream, means3D, img, dvec, cov3D,
                       l2i, W1, b1, W2, b2, out);
  }
}

// Round 7
// 83.545 us; speedup vs baseline: 1.1967x; 1.1737x over previous
//
#include <hip/hip_runtime.h>
#include <hip/hip_bf16.h>
#include <math.h>

#define BN 12
#define HG 28
#define WG 60
#define LL 1680      // HG*WG
#define CC 128
#define P2 20
#define HID 256
#define NPTS (BN * LL * P2)  // 403200
#define NPB 64               // points per block in gemm kernel
#define NWG (NPTS / NPB)     // 6300

static constexpr size_t OUT_CAM_OFF = (size_t)BN * LL * P2 * CC;              // 51609600
static constexpr size_t OUT_PTS_OFF = OUT_CAM_OFF + (size_t)BN * LL * P2 * 2; // 52416000

typedef short v8s __attribute__((ext_vector_type(8)));
typedef float v4f __attribute__((ext_vector_type(4)));
typedef unsigned long long u64;

__device__ __forceinline__ unsigned short f2bf(float f) {
  unsigned x = __float_as_uint(f);
  unsigned r = (x + 0x7FFFu + ((x >> 16) & 1u)) >> 16;
  return (unsigned short)r;
}

// ---------------- prep: transpose img (BN,C,L)->(BN,L,C)  ||  pack W2 to bf16 frags ---------
// blocks 0..647: transpose tiles (12 bn x 2 c-tiles x 27 l-tiles). blocks 648..663: W2 pack.
__global__ __launch_bounds__(256) void prep_k(const float* __restrict__ img,
                                              float* __restrict__ featT,
                                              const float* __restrict__ W2,
                                              unsigned short* __restrict__ W2bf) {
  const int b = blockIdx.x;
  const int t = threadIdx.x;
  if (b < 648) {
    __shared__ float tile[64][65];
    const int bz = b / 54;         // bn
    const int rem = b - bz * 54;
    const int by = rem / 27;       // c-tile
    const int bx = rem - by * 27;  // l-tile
    const int c0 = by * 64;
    const int l0 = bx * 64;
    {
      const int lx = t & 63;
      const int cy = t >> 6;
#pragma unroll
      for (int i = 0; i < 64; i += 4) {
        const int c = c0 + cy + i;
        const int l = l0 + lx;
        float v = 0.f;
        if (l < LL) v = img[((size_t)bz * CC + c) * LL + l];
        tile[cy + i][lx] = v;
      }
    }
    __syncthreads();
    {
      const int cx = t & 63;
      const int ly = t >> 6;
#pragma unroll
      for (int i = 0; i < 64; i += 4) {
        const int l = l0 + ly + i;
        const int c = c0 + cx;
        if (l < LL) featT[((size_t)bz * LL + l) * CC + c] = tile[cx][ly + i];
      }
    }
  } else {
    // W2 (256x128 f32) -> bf16 B-fragment order: entry u: cg=u>>9, ks=(u>>6)&7, lane=u&63;
    // 8 bf16 from W2[ks*32 + (lane>>4)*8 + e][cg*16 + (lane&15)]
    const int u = (b - 648) * 256 + t;
    if (u < 4096) {
      const int lane = u & 63;
      const int ks = (u >> 6) & 7;
      const int cg = u >> 9;
      const int col = cg * 16 + (lane & 15);
      const int kb = ks * 32 + (lane >> 4) * 8;
      v8s r;
#pragma unroll
      for (int e = 0; e < 8; ++e) r[e] = (short)f2bf(W2[(size_t)(kb + e) * CC + col]);
      *(v8s*)(W2bf + (size_t)u * 8) = r;
    }
  }
}

// ---------------- kernel A: geometry -> cam/pts outputs ONLY ----------------
// Projection math FROZEN (passing R3/R5/R6). cam = cx/homo amplifies contraction-order noise
// near the homo clamp ~1e6x; keep this expression tree byte-identical, in its own kernel.
__global__ __launch_bounds__(256) void geom_k(const float* __restrict__ means3D,
                                              const float* __restrict__ dvec,
                                              const float* __restrict__ cov3D,
                                              const float* __restrict__ l2i,
                                              float* __restrict__ out) {
  const int pid = blockIdx.x * 256 + threadIdx.x;
  if (pid >= NPTS) return;
  const unsigned qg = (unsigned)pid / P2;
  const int p = pid - (int)qg * P2;
  const unsigned bn = qg / LL;

  const size_t base3 = (size_t)qg * 3;
  const float m0 = means3D[base3 + 0], m1 = means3D[base3 + 1], m2 = means3D[base3 + 2];
  const float d0 = dvec[base3 + 0], d1 = dvec[base3 + 1], d2 = dvec[base3 + 2];
  const float* cv = cov3D + (size_t)qg * 9;
  const float q = d0 * (cv[0] * d0 + cv[1] * d1 + cv[2] * d2) +
                  d1 * (cv[3] * d0 + cv[4] * d1 + cv[5] * d2) +
                  d2 * (cv[6] * d0 + cv[7] * d1 + cv[8] * d2);
  const float s = sqrtf(q);
  const int k = p >> 2, j = p & 3;
  const float a = (-1.5f + 0.75f * (float)k) * s;     // lin5[k]*sqrt(q)
  const float tt = -0.5f + (1.0f / 3.0f) * (float)j;  // linP[j]
  const float px = m0 + a * d0 + tt * d1;             // orth=(d1,-d0,0)
  const float py = m1 + a * d1 - tt * d0;
  const float pz = m2 + a * d2;
  const float* M = l2i + (size_t)bn * 16;
  const float cx = M[0] * px + M[1] * py + M[2] * pz + M[3];
  const float cy = M[4] * px + M[5] * py + M[6] * pz + M[7];
  const float cz = M[8] * px + M[9] * py + M[10] * pz + M[11];
  const float homo = fmaxf(cz, 1e-6f);
  const float u = cx / homo;
  const float v = cy / homo;

  *(float2*)(out + OUT_CAM_OFF + (size_t)pid * 2) = make_float2(u, v);
  float* ptso = out + OUT_PTS_OFF + (size_t)pid * 3;
  ptso[0] = px;
  ptso[1] = py;
  ptso[2] = pz;
}

// ---------------- kernel B: MLP via MFMA + bilinear gather + coalesced write ----------------
// R7 change vs validated R6: per-point records (off/w/pn) are NOT round-tripped through ws;
// threads 0..63 read back this block's cam/pts from `out` (disjoint region from the feats
// this kernel writes) and re-derive them. Bilinear is continuous, so ulp-level recompute
// differences at pixel boundaries carry ~zero weight. Phases A/B/epilogue identical to R6.
__global__ __launch_bounds__(256, 4) void gemm_k(
    const float* __restrict__ featT,  // (BN,L,C)
    const float* __restrict__ W1,
    const float* __restrict__ b1,
    const unsigned short* __restrict__ W2bf,
    const float* __restrict__ b2,
    float* __restrict__ out) {
  const int tid = threadIdx.x;
  const int wgid = blockIdx.x;
  const int gp0 = wgid * NPB;
  const int bn = wgid / 525;  // 33600 points per bn / 64; blocks never span bn

  __shared__ __align__(16) char sH[NPB * 512];
  __shared__ u64 sOff8[NPB];
  __shared__ float4 sWl[NPB];
  __shared__ float4 sPnl[NPB];

  const int wv = tid >> 6;
  const int lane = tid & 63;
  const int lrow = lane & 15;
  const int g = lane >> 4;

  // B-fragments for this wave's 32 channels (issued early; latency hides under staging)
  v8s fb0[8], fb1[8];
#pragma unroll
  for (int ks = 0; ks < 8; ++ks) {
    fb0[ks] = *(const v8s*)(W2bf + (size_t)(((wv * 2 + 0) * 8 + ks) * 64 + lane) * 8);
    fb1[ks] = *(const v8s*)(W2bf + (size_t)(((wv * 2 + 1) * 8 + ks) * 64 + lane) * 8);
  }

  // W1/b1 slice: loaded ONCE (loop-invariant per thread)
  const int h4 = (tid & 63) * 4;
  const int pw = tid >> 6;
  const float4 a0 = *(const float4*)(W1 + h4);
  const float4 a1 = *(const float4*)(W1 + HID + h4);
  const float4 a2 = *(const float4*)(W1 + 2 * HID + h4);
  const float4 bb = *(const float4*)(b1 + h4);

  // stage: read back cam/pts for this block's 64 points, derive bilinear records + pn
  if (tid < NPB) {
    const int pid = gp0 + tid;
    const float2 cm = *(const float2*)(out + OUT_CAM_OFF + (size_t)pid * 2);
    const float u = cm.x, v = cm.y;
    const float* ptso = out + OUT_PTS_OFF + (size_t)pid * 3;
    const float px = ptso[0], py = ptso[1], pz = ptso[2];

    const float x = u * 0.125f - 0.5f;
    const float y = v * 0.125f - 0.5f;
    const float x0f = floorf(x), y0f = floorf(y);
    const float wx = x - x0f, wy = y - y0f;
    const bool vx0 = (x0f >= 0.f) && (x0f < (float)WG);
    const bool vx1 = (x0f + 1.f >= 0.f) && (x0f + 1.f < (float)WG);
    const bool vy0 = (y0f >= 0.f) && (y0f < (float)HG);
    const bool vy1 = (y0f + 1.f >= 0.f) && (y0f + 1.f < (float)HG);
    const unsigned ix0 = (unsigned)(int)fminf(fmaxf(x0f, 0.f), (float)(WG - 1));
    const unsigned ix1 = (unsigned)(int)fminf(fmaxf(x0f + 1.f, 0.f), (float)(WG - 1));
    const unsigned iy0 = (unsigned)(int)fminf(fmaxf(y0f, 0.f), (float)(HG - 1));
    const unsigned iy1 = (unsigned)(int)fminf(fmaxf(y0f + 1.f, 0.f), (float)(HG - 1));
    sOff8[tid] = (u64)(iy0 * WG + ix0) | ((u64)(iy0 * WG + ix1) << 16) |
                 ((u64)(iy1 * WG + ix0) << 32) | ((u64)(iy1 * WG + ix1) << 48);
    sWl[tid] = make_float4((vx0 && vy0) ? (1.f - wx) * (1.f - wy) : 0.f,
                           (vx1 && vy0) ? wx * (1.f - wy) : 0.f,
                           (vx0 && vy1) ? (1.f - wx) * wy : 0.f,
                           (vx1 && vy1) ? wx * wy : 0.f);
    sPnl[tid] = make_float4(fminf(fmaxf((px + 50.f) * 0.01f, 0.f), 1.f),
                            fminf(fmaxf((py + 50.f) * 0.01f, 0.f), 1.f),
                            fminf(fmaxf((pz + 4.f) * 0.125f, 0.f), 1.f), 0.f);
  }
  __syncthreads();

  // phase A: H[64][256] = relu(pn @ W1 + b1) -> bf16 LDS (swizzled), b64 writes
#pragma unroll
  for (int it = 0; it < NPB / 4; ++it) {
    const int p = it * 4 + pw;
    const float4 pn = sPnl[p];
    const float v0 = fmaxf(bb.x + pn.x * a0.x + pn.y * a1.x + pn.z * a2.x, 0.f);
    const float v1 = fmaxf(bb.y + pn.x * a0.y + pn.y * a1.y + pn.z * a2.y, 0.f);
    const float v2 = fmaxf(bb.z + pn.x * a0.z + pn.y * a1.z + pn.z * a2.z, 0.f);
    const float v3 = fmaxf(bb.w + pn.x * a0.w + pn.y * a1.w + pn.z * a2.w, 0.f);
    __hip_bfloat162 plo = __float22bfloat162_rn(make_float2(v0, v1));
    __hip_bfloat162 phi = __float22bfloat162_rn(make_float2(v2, v3));
    const unsigned ulo = *reinterpret_cast<const unsigned*>(&plo);
    const unsigned uhi = *reinterpret_cast<const unsigned*>(&phi);
    const u64 pk = (u64)ulo | ((u64)uhi << 32);
    *(u64*)(sH + p * 512 + (((unsigned)(h4 * 2)) ^ (((unsigned)(p & 7)) << 4))) = pk;
  }
  __syncthreads();

  // phase B: tile pairs {0,1},{2,3}: MFMA both -> barrier -> transpose both -> barrier
#pragma unroll
  for (int pg2 = 0; pg2 < 2; ++pg2) {
    v4f acc[2][2];
#pragma unroll
    for (int i = 0; i < 2; ++i)
#pragma unroll
      for (int c = 0; c < 2; ++c) acc[i][c] = (v4f){0.f, 0.f, 0.f, 0.f};

#pragma unroll
    for (int pth = 0; pth < 2; ++pth) {
      const int pt = pg2 * 2 + pth;
      const int arow = pt * 16 + lrow;
      const unsigned swz = ((unsigned)(arow & 7)) << 4;
      v8s fa[8];
#pragma unroll
      for (int ks = 0; ks < 8; ++ks)
        fa[ks] = *(const v8s*)(sH + arow * 512 + (((unsigned)(ks * 64 + g * 16)) ^ swz));
#pragma unroll
      for (int ks = 0; ks < 8; ++ks)
        acc[pth][0] = __builtin_amdgcn_mfma_f32_16x16x32_bf16(fa[ks], fb0[ks], acc[pth][0], 0, 0, 0);
#pragma unroll
      for (int ks = 0; ks < 8; ++ks)
        acc[pth][1] = __builtin_amdgcn_mfma_f32_16x16x32_bf16(fa[ks], fb1[ks], acc[pth][1], 0, 0, 0);
    }
    __syncthreads();  // all waves done reading rows of this tile pair
#pragma unroll
    for (int pth = 0; pth < 2; ++pth) {
      const int pt = pg2 * 2 + pth;
#pragma unroll
      for (int r = 0; r < 4; ++r) {
        const int lp = pt * 16 + g * 4 + r;  // C/D: row=(lane>>4)*4+r, col=lane&15
        const unsigned s2 = ((unsigned)(lp & 7)) << 4;
        const int c0 = wv * 32 + lrow;
        *(float*)(sH + lp * 512 + (((unsigned)(c0 * 4)) ^ s2)) = acc[pth][0][r];
        *(float*)(sH + lp * 512 + (((unsigned)((c0 + 16) * 4)) ^ s2)) = acc[pth][1][r];
      }
    }
    __syncthreads();  // writes visible before next pair / epilogue
  }

  // epilogue: bias + bilinear gather + fully-coalesced float4 stores
  const float* featc = featT + (size_t)bn * (LL * CC);
#pragma unroll
  for (int it = 0; it < 8; ++it) {
    const int p = it * 8 + (tid >> 5);
    const int c4g = tid & 31;
    const unsigned boff =
        (unsigned)(p * 512) + (((unsigned)(c4g * 16)) ^ (((unsigned)(p & 7)) << 4));
    const v4f t = *(const v4f*)(sH + boff);
    const u64 o8 = sOff8[p];
    const float4 w = sWl[p];
    const float4 bias = *(const float4*)(b2 + c4g * 4);
    float rx = t[0] + bias.x, ry = t[1] + bias.y, rz = t[2] + bias.z, rw = t[3] + bias.w;
    {
      const float4 f = *(const float4*)(featc + (size_t)(unsigned)(o8 & 0xFFFFu) * CC + c4g * 4);
      rx += w.x * f.x; ry += w.x * f.y; rz += w.x * f.z; rw += w.x * f.w;
    }
    {
      const float4 f =
          *(const float4*)(featc + (size_t)(unsigned)((o8 >> 16) & 0xFFFFu) * CC + c4g * 4);
      rx += w.y * f.x; ry += w.y * f.y; rz += w.y * f.z; rw += w.y * f.w;
    }
    {
      const float4 f =
          *(const float4*)(featc + (size_t)(unsigned)((o8 >> 32) & 0xFFFFu) * CC + c4g * 4);
      rx += w.z * f.x; ry += w.z * f.y; rz += w.z * f.z; rw += w.z * f.w;
    }
    {
      const float4 f =
          *(const float4*)(featc + (size_t)(unsigned)((o8 >> 48) & 0xFFFFu) * CC + c4g * 4);
      rx += w.w * f.x; ry += w.w * f.y; rz += w.w * f.z; rw += w.w * f.w;
    }
    *(float4*)(out + (size_t)(gp0 + p) * CC + c4g * 4) = make_float4(rx, ry, rz, rw);
  }
}

// ---------------- last-resort fallback (no ws): fused fp32 kernel ----------------
__global__ __launch_bounds__(128) void gauss_fb(
    const float* __restrict__ means3D, const float* __restrict__ feat,
    const float* __restrict__ dvec, const float* __restrict__ cov3D,
    const float* __restrict__ l2i, const float* __restrict__ W1,
    const float* __restrict__ b1, const float* __restrict__ W2,
    const float* __restrict__ b2, float* __restrict__ out) {
  const int l = blockIdx.x;
  const int bn = blockIdx.y;
  const int tid = threadIdx.x;
  __shared__ float sH[P2][HID];
  __shared__ float sPn[P2][3];
  __shared__ float sW[P2][4];
  __shared__ int sOff[P2][4];
  if (tid < P2) {
    const int p = tid;
    const size_t base3 = ((size_t)bn * LL + l) * 3;
    const float m0 = means3D[base3 + 0], m1 = means3D[base3 + 1], m2 = means3D[base3 + 2];
    const float d0 = dvec[base3 + 0], d1 = dvec[base3 + 1], d2 = dvec[base3 + 2];
    const float* cv = cov3D + ((size_t)bn * LL + l) * 9;
    const float q = d0 * (cv[0] * d0 + cv[1] * d1 + cv[2] * d2) +
                    d1 * (cv[3] * d0 + cv[4] * d1 + cv[5] * d2) +
                    d2 * (cv[6] * d0 + cv[7] * d1 + cv[8] * d2);
    const float s = sqrtf(q);
    const int k = p >> 2, j = p & 3;
    const float a = (-1.5f + 0.75f * (float)k) * s;
    const float tt = -0.5f + (1.0f / 3.0f) * (float)j;
    const float px = m0 + a * d0 + tt * d1;
    const float py = m1 + a * d1 - tt * d0;
    const float pz = m2 + a * d2;
    const float* M = l2i + (size_t)bn * 16;
    const float cx = M[0] * px + M[1] * py + M[2] * pz + M[3];
    const float cy = M[4] * px + M[5] * py + M[6] * pz + M[7];
    const float cz = M[8] * px + M[9] * py + M[10] * pz + M[11];
    const float homo = fmaxf(cz, 1e-6f);
    const float u = cx / homo;
    const float v = cy / homo;
    float* camo = out + OUT_CAM_OFF + (((size_t)bn * LL + l) * P2 + p) * 2;
    camo[0] = u;
    camo[1] = v;
    float* ptso = out + OUT_PTS_OFF + (((size_t)bn * LL + l) * P2 + p) * 3;
    ptso[0] = px;
    ptso[1] = py;
    ptso[2] = pz;
    const float x = u * 0.125f - 0.5f;
    const float y = v * 0.125f - 0.5f;
    const float x0f = floorf(x), y0f = floorf(y);
    const float wx = x - x0f, wy = y - y0f;
    const bool vx0 = (x0f >= 0.f) && (x0f < (float)WG);
    const bool vx1 = (x0f + 1.f >= 0.f) && (x0f + 1.f < (float)WG);
    const bool vy0 = (y0f >= 0.f) && (y0f < (float)HG);
    const bool vy1 = (y0f + 1.f >= 0.f) && (y0f + 1.f < (float)HG);
    const int ix0 = (int)fminf(fmaxf(x0f, 0.f), (float)(WG - 1));
    const int ix1 = (int)fminf(fmaxf(x0f + 1.f, 0.f), (float)(WG - 1));
    const int iy0 = (int)fminf(fmaxf(y0f, 0.f), (float)(HG - 1));
    const int iy1 = (int)fminf(fmaxf(y0f + 1.f, 0.f), (float)(HG - 1));
    sOff[p][0] = iy0 * WG + ix0;
    sOff[p][1] = iy0 * WG + ix1;
    sOff[p][2] = iy1 * WG + ix0;
    sOff[p][3] = iy1 * WG + ix1;
    sW[p][0] = (vx0 && vy0) ? (1.f - wx) * (1.f - wy) : 0.f;
    sW[p][1] = (vx1 && vy0) ? wx * (1.f - wy) : 0.f;
    sW[p][2] = (vx0 && vy1) ? (1.f - wx) * wy : 0.f;
    sW[p][3] = (vx1 && vy1) ? wx * wy : 0.f;
    sPn[p][0] = fminf(fmaxf((px + 50.f) * 0.01f, 0.f), 1.f);
    sPn[p][1] = fminf(fmaxf((py + 50.f) * 0.01f, 0.f), 1.f);
    sPn[p][2] = fminf(fmaxf((pz + 4.f) * 0.125f, 0.f), 1.f);
  }
  __syncthreads();
  for (int u0 = tid; u0 < P2 * HID; u0 += 128) {
    const int p = u0 >> 8;
    const int h = u0 & (HID - 1);
    const float v = b1[h] + sPn[p][0] * W1[h] + sPn[p][1] * W1[HID + h] + sPn[p][2] * W1[2 * HID + h];
    sH[p][h] = fmaxf(v, 0.f);
  }
  __syncthreads();
  const int pg = tid >> 5;
  const int c0 = (tid & 31) * 4;
  const int pbase = pg * 5;
  float acc[5][4];
#pragma unroll
  for (int i = 0; i < 5; ++i)
#pragma unroll
    for (int j2 = 0; j2 < 4; ++j2) acc[i][j2] = 0.f;
  for (int h = 0; h < HID; h += 4) {
    const float4 w0 = *(const float4*)(W2 + (size_t)(h + 0) * CC + c0);
    const float4 w1 = *(const float4*)(W2 + (size_t)(h + 1) * CC + c0);
    const float4 w2 = *(const float4*)(W2 + (size_t)(h + 2) * CC + c0);
    const float4 w3 = *(const float4*)(W2 + (size_t)(h + 3) * CC + c0);
#pragma unroll
    for (int i = 0; i < 5; ++i) {
      const float4 hv = *(const float4*)(&sH[pbase + i][h]);
      acc[i][0] += hv.x * w0.x + hv.y * w1.x + hv.z * w2.x + hv.w * w3.x;
      acc[i][1] += hv.x * w0.y + hv.y * w1.y + hv.z * w2.y + hv.w * w3.y;
      acc[i][2] += hv.x * w0.z + hv.y * w1.z + hv.z * w2.z + hv.w * w3.z;
      acc[i][3] += hv.x * w0.w + hv.y * w1.w + hv.z * w2.w + hv.w * w3.w;
    }
  }
  const float4 bias = *(const float4*)(b2 + c0);
  const float* fbase = feat + (size_t)bn * CC * LL;
#pragma unroll
  for (int i = 0; i < 5; ++i) {
    const int p = pbase + i;
    float4 r;
    r.x = acc[i][0] + bias.x;
    r.y = acc[i][1] + bias.y;
    r.z = acc[i][2] + bias.z;
    r.w = acc[i][3] + bias.w;
#pragma unroll
    for (int corner = 0; corner < 4; ++corner) {
      const float w = sW[p][corner];
      const int off = sOff[p][corner];
      r.x += w * fbase[(size_t)(c0 + 0) * LL + off];
      r.y += w * fbase[(size_t)(c0 + 1) * LL + off];
      r.z += w * fbase[(size_t)(c0 + 2) * LL + off];
      r.w += w * fbase[(size_t)(c0 + 3) * LL + off];
    }
    *(float4*)(out + (((size_t)bn * LL + l) * P2 + p) * CC + c0) = r;
  }
}

extern "C" void kernel_launch(void* const* d_in, const int* in_sizes, int n_in,
                              void* d_out, int out_size, void* d_ws, size_t ws_size,
                              hipStream_t stream) {
  const float* means3D = (const float*)d_in[0];
  const float* img = (const float*)d_in[1];
  const float* dvec = (const float*)d_in[2];
  const float* cov3D = (const float*)d_in[3];
  const float* l2i = (const float*)d_in[4];
  const float* W1 = (const float*)d_in[5];
  const float* b1 = (const float*)d_in[6];
  const float* W2 = (const float*)d_in[7];
  const float* b2 = (const float*)d_in[8];
  float* out = (float*)d_out;

  const size_t w2bf_bytes = 65536;
  const size_t tbytes = (size_t)BN * LL * CC * sizeof(float);  // 10321920

  if (ws_size >= w2bf_bytes + tbytes) {
    unsigned short* W2bf = (unsigned short*)d_ws;
    float* featT = (float*)((char*)d_ws + w2bf_bytes);
    hipLaunchKernelGGL(prep_k, dim3(648 + 16), dim3(256), 0, stream, img, featT, W2, W2bf);
    hipLaunchKernelGGL(geom_k, dim3(NPTS / 256), dim3(256), 0, stream, means3D, dvec, cov3D,
                       l2i, out);
    hipLaunchKernelGGL(gemm_k, dim3(NWG), dim3(256), 0, stream, featT, W1, b1, W2bf, b2, out);
  } else {
    hipLaunchKernelGGL(gauss_fb, dim3(LL, BN), dim3(128), 0, stream, means3D, img, dvec, cov3D,
                       l2i, W1, b1, W2, b2, out);
  }
}

// Round 8
// 79.628 us; speedup vs baseline: 1.2555x; 1.0492x over previous
//
#include <hip/hip_runtime.h>
#include <hip/hip_bf16.h>
#include <math.h>

#define BN 12
#define HG 28
#define WG 60
#define LL 1680      // HG*WG
#define CC 128
#define P2 20
#define HID 256
#define NPTS (BN * LL * P2)  // 403200
#define NPB 64               // points per block in gemm kernel
#define NWG (NPTS / NPB)     // 6300

static constexpr size_t OUT_CAM_OFF = (size_t)BN * LL * P2 * CC;              // 51609600
static constexpr size_t OUT_PTS_OFF = OUT_CAM_OFF + (size_t)BN * LL * P2 * 2; // 52416000

typedef short v8s __attribute__((ext_vector_type(8)));
typedef float v4f __attribute__((ext_vector_type(4)));
typedef unsigned long long u64;

__device__ __forceinline__ unsigned short f2bf(float f) {
  unsigned x = __float_as_uint(f);
  unsigned r = (x + 0x7FFFu + ((x >> 16) & 1u)) >> 16;
  return (unsigned short)r;
}

// ---------------- prep: transpose img (BN,C,L)->(BN,L,C)  ||  pack W2 to bf16 frags ---------
// Validated in R7. blocks 0..647: transpose tiles. blocks 648..663: W2 pack.
__global__ __launch_bounds__(256) void prep_k(const float* __restrict__ img,
                                              float* __restrict__ featT,
                                              const float* __restrict__ W2,
                                              unsigned short* __restrict__ W2bf) {
  const int b = blockIdx.x;
  const int t = threadIdx.x;
  if (b < 648) {
    __shared__ float tile[64][65];
    const int bz = b / 54;         // bn
    const int rem = b - bz * 54;
    const int by = rem / 27;       // c-tile
    const int bx = rem - by * 27;  // l-tile
    const int c0 = by * 64;
    const int l0 = bx * 64;
    {
      const int lx = t & 63;
      const int cy = t >> 6;
#pragma unroll
      for (int i = 0; i < 64; i += 4) {
        const int c = c0 + cy + i;
        const int l = l0 + lx;
        float v = 0.f;
        if (l < LL) v = img[((size_t)bz * CC + c) * LL + l];
        tile[cy + i][lx] = v;
      }
    }
    __syncthreads();
    {
      const int cx = t & 63;
      const int ly = t >> 6;
#pragma unroll
      for (int i = 0; i < 64; i += 4) {
        const int l = l0 + ly + i;
        const int c = c0 + cx;
        if (l < LL) featT[((size_t)bz * LL + l) * CC + c] = tile[cx][ly + i];
      }
    }
  } else {
    const int u = (b - 648) * 256 + t;
    if (u < 4096) {
      const int lane = u & 63;
      const int ks = (u >> 6) & 7;
      const int cg = u >> 9;
      const int col = cg * 16 + (lane & 15);
      const int kb = ks * 32 + (lane >> 4) * 8;
      v8s r;
#pragma unroll
      for (int e = 0; e < 8; ++e) r[e] = (short)f2bf(W2[(size_t)(kb + e) * CC + col]);
      *(v8s*)(W2bf + (size_t)u * 8) = r;
    }
  }
}

// ---------------- kernel A: geometry -> cam/pts outputs ONLY ----------------
// Projection math FROZEN (passing R3/R5/R6/R7). cam = cx/homo amplifies contraction-order
// noise near the homo clamp ~1e6x; keep this expression tree byte-identical, own kernel.
__global__ __launch_bounds__(256) void geom_k(const float* __restrict__ means3D,
                                              const float* __restrict__ dvec,
                                              const float* __restrict__ cov3D,
                                              const float* __restrict__ l2i,
                                              float* __restrict__ out) {
  const int pid = blockIdx.x * 256 + threadIdx.x;
  if (pid >= NPTS) return;
  const unsigned qg = (unsigned)pid / P2;
  const int p = pid - (int)qg * P2;
  const unsigned bn = qg / LL;

  const size_t base3 = (size_t)qg * 3;
  const float m0 = means3D[base3 + 0], m1 = means3D[base3 + 1], m2 = means3D[base3 + 2];
  const float d0 = dvec[base3 + 0], d1 = dvec[base3 + 1], d2 = dvec[base3 + 2];
  const float* cv = cov3D + (size_t)qg * 9;
  const float q = d0 * (cv[0] * d0 + cv[1] * d1 + cv[2] * d2) +
                  d1 * (cv[3] * d0 + cv[4] * d1 + cv[5] * d2) +
                  d2 * (cv[6] * d0 + cv[7] * d1 + cv[8] * d2);
  const float s = sqrtf(q);
  const int k = p >> 2, j = p & 3;
  const float a = (-1.5f + 0.75f * (float)k) * s;     // lin5[k]*sqrt(q)
  const float tt = -0.5f + (1.0f / 3.0f) * (float)j;  // linP[j]
  const float px = m0 + a * d0 + tt * d1;             // orth=(d1,-d0,0)
  const float py = m1 + a * d1 - tt * d0;
  const float pz = m2 + a * d2;
  const float* M = l2i + (size_t)bn * 16;
  const float cx = M[0] * px + M[1] * py + M[2] * pz + M[3];
  const float cy = M[4] * px + M[5] * py + M[6] * pz + M[7];
  const float cz = M[8] * px + M[9] * py + M[10] * pz + M[11];
  const float homo = fmaxf(cz, 1e-6f);
  const float u = cx / homo;
  const float v = cy / homo;

  *(float2*)(out + OUT_CAM_OFF + (size_t)pid * 2) = make_float2(u, v);
  float* ptso = out + OUT_PTS_OFF + (size_t)pid * 3;
  ptso[0] = px;
  ptso[1] = py;
  ptso[2] = pz;
}

// ---------------- kernel B: MLP via MFMA + bilinear gather + coalesced write ----------------
// R8 change vs validated R7: epilogue interleaved per tile-pair. After pair {0,1}'s
// transpose barrier, epilogue pts 0..31 runs immediately (rows 0..31 final; pair {2,3}
// touches only rows 32..63 -> no hazard). Spreads L2 gathers + HBM stores across the
// kernel instead of an end-of-block burst. Per-point math byte-identical to R7.
__global__ __launch_bounds__(256, 4) void gemm_k(
    const float* __restrict__ featT,  // (BN,L,C)
    const float* __restrict__ W1,
    const float* __restrict__ b1,
    const unsigned short* __restrict__ W2bf,
    const float* __restrict__ b2,
    float* __restrict__ out) {
  const int tid = threadIdx.x;
  const int wgid = blockIdx.x;
  const int gp0 = wgid * NPB;
  const int bn = wgid / 525;  // 33600 points per bn / 64; blocks never span bn

  __shared__ __align__(16) char sH[NPB * 512];
  __shared__ u64 sOff8[NPB];
  __shared__ float4 sWl[NPB];
  __shared__ float4 sPnl[NPB];

  const int wv = tid >> 6;
  const int lane = tid & 63;
  const int lrow = lane & 15;
  const int g = lane >> 4;

  // B-fragments for this wave's 32 channels (issued early; latency hides under staging)
  v8s fb0[8], fb1[8];
#pragma unroll
  for (int ks = 0; ks < 8; ++ks) {
    fb0[ks] = *(const v8s*)(W2bf + (size_t)(((wv * 2 + 0) * 8 + ks) * 64 + lane) * 8);
    fb1[ks] = *(const v8s*)(W2bf + (size_t)(((wv * 2 + 1) * 8 + ks) * 64 + lane) * 8);
  }

  // W1/b1 slice: loaded ONCE (loop-invariant per thread)
  const int h4 = (tid & 63) * 4;
  const int pw = tid >> 6;
  const float4 a0 = *(const float4*)(W1 + h4);
  const float4 a1 = *(const float4*)(W1 + HID + h4);
  const float4 a2 = *(const float4*)(W1 + 2 * HID + h4);
  const float4 bb = *(const float4*)(b1 + h4);

  // stage: read back cam/pts for this block's 64 points, derive bilinear records + pn
  if (tid < NPB) {
    const int pid = gp0 + tid;
    const float2 cm = *(const float2*)(out + OUT_CAM_OFF + (size_t)pid * 2);
    const float u = cm.x, v = cm.y;
    const float* ptso = out + OUT_PTS_OFF + (size_t)pid * 3;
    const float px = ptso[0], py = ptso[1], pz = ptso[2];

    const float x = u * 0.125f - 0.5f;
    const float y = v * 0.125f - 0.5f;
    const float x0f = floorf(x), y0f = floorf(y);
    const float wx = x - x0f, wy = y - y0f;
    const bool vx0 = (x0f >= 0.f) && (x0f < (float)WG);
    const bool vx1 = (x0f + 1.f >= 0.f) && (x0f + 1.f < (float)WG);
    const bool vy0 = (y0f >= 0.f) && (y0f < (float)HG);
    const bool vy1 = (y0f + 1.f >= 0.f) && (y0f + 1.f < (float)HG);
    const unsigned ix0 = (unsigned)(int)fminf(fmaxf(x0f, 0.f), (float)(WG - 1));
    const unsigned ix1 = (unsigned)(int)fminf(fmaxf(x0f + 1.f, 0.f), (float)(WG - 1));
    const unsigned iy0 = (unsigned)(int)fminf(fmaxf(y0f, 0.f), (float)(HG - 1));
    const unsigned iy1 = (unsigned)(int)fminf(fmaxf(y0f + 1.f, 0.f), (float)(HG - 1));
    sOff8[tid] = (u64)(iy0 * WG + ix0) | ((u64)(iy0 * WG + ix1) << 16) |
                 ((u64)(iy1 * WG + ix0) << 32) | ((u64)(iy1 * WG + ix1) << 48);
    sWl[tid] = make_float4((vx0 && vy0) ? (1.f - wx) * (1.f - wy) : 0.f,
                           (vx1 && vy0) ? wx * (1.f - wy) : 0.f,
                           (vx0 && vy1) ? (1.f - wx) * wy : 0.f,
                           (vx1 && vy1) ? wx * wy : 0.f);
    sPnl[tid] = make_float4(fminf(fmaxf((px + 50.f) * 0.01f, 0.f), 1.f),
                            fminf(fmaxf((py + 50.f) * 0.01f, 0.f), 1.f),
                            fminf(fmaxf((pz + 4.f) * 0.125f, 0.f), 1.f), 0.f);
  }
  __syncthreads();

  // phase A: H[64][256] = relu(pn @ W1 + b1) -> bf16 LDS (swizzled), b64 writes
#pragma unroll
  for (int it = 0; it < NPB / 4; ++it) {
    const int p = it * 4 + pw;
    const float4 pn = sPnl[p];
    const float v0 = fmaxf(bb.x + pn.x * a0.x + pn.y * a1.x + pn.z * a2.x, 0.f);
    const float v1 = fmaxf(bb.y + pn.x * a0.y + pn.y * a1.y + pn.z * a2.y, 0.f);
    const float v2 = fmaxf(bb.z + pn.x * a0.z + pn.y * a1.z + pn.z * a2.z, 0.f);
    const float v3 = fmaxf(bb.w + pn.x * a0.w + pn.y * a1.w + pn.z * a2.w, 0.f);
    __hip_bfloat162 plo = __float22bfloat162_rn(make_float2(v0, v1));
    __hip_bfloat162 phi = __float22bfloat162_rn(make_float2(v2, v3));
    const unsigned ulo = *reinterpret_cast<const unsigned*>(&plo);
    const unsigned uhi = *reinterpret_cast<const unsigned*>(&phi);
    const u64 pk = (u64)ulo | ((u64)uhi << 32);
    *(u64*)(sH + p * 512 + (((unsigned)(h4 * 2)) ^ (((unsigned)(p & 7)) << 4))) = pk;
  }
  __syncthreads();

  const float* featc = featT + (size_t)bn * (LL * CC);

  // phase B + interleaved epilogue: per pair {0,1},{2,3}:
  // MFMA both -> bar -> transpose both -> bar -> epilogue of this pair's 32 points
#pragma unroll
  for (int pg2 = 0; pg2 < 2; ++pg2) {
    v4f acc[2][2];
#pragma unroll
    for (int i = 0; i < 2; ++i)
#pragma unroll
      for (int c = 0; c < 2; ++c) acc[i][c] = (v4f){0.f, 0.f, 0.f, 0.f};

#pragma unroll
    for (int pth = 0; pth < 2; ++pth) {
      const int pt = pg2 * 2 + pth;
      const int arow = pt * 16 + lrow;
      const unsigned swz = ((unsigned)(arow & 7)) << 4;
      v8s fa[8];
#pragma unroll
      for (int ks = 0; ks < 8; ++ks)
        fa[ks] = *(const v8s*)(sH + arow * 512 + (((unsigned)(ks * 64 + g * 16)) ^ swz));
#pragma unroll
      for (int ks = 0; ks < 8; ++ks)
        acc[pth][0] = __builtin_amdgcn_mfma_f32_16x16x32_bf16(fa[ks], fb0[ks], acc[pth][0], 0, 0, 0);
#pragma unroll
      for (int ks = 0; ks < 8; ++ks)
        acc[pth][1] = __builtin_amdgcn_mfma_f32_16x16x32_bf16(fa[ks], fb1[ks], acc[pth][1], 0, 0, 0);
    }
    __syncthreads();  // all waves done reading this pair's bf16 rows
#pragma unroll
    for (int pth = 0; pth < 2; ++pth) {
      const int pt = pg2 * 2 + pth;
#pragma unroll
      for (int r = 0; r < 4; ++r) {
        const int lp = pt * 16 + g * 4 + r;  // C/D: row=(lane>>4)*4+r, col=lane&15
        const unsigned s2 = ((unsigned)(lp & 7)) << 4;
        const int c0 = wv * 32 + lrow;
        *(float*)(sH + lp * 512 + (((unsigned)(c0 * 4)) ^ s2)) = acc[pth][0][r];
        *(float*)(sH + lp * 512 + (((unsigned)((c0 + 16) * 4)) ^ s2)) = acc[pth][1][r];
      }
    }
    __syncthreads();  // transposed f32 rows of this pair visible to all waves

    // epilogue for this pair's 32 points (rows pg2*32 .. pg2*32+31); next pair's MFMA
    // reads rows (1-pg2)*32.. which this phase never touches -> no extra barrier needed.
#pragma unroll
    for (int it = 0; it < 4; ++it) {
      const int p = pg2 * 32 + it * 8 + (tid >> 5);
      const int c4g = tid & 31;
      const unsigned boff =
          (unsigned)(p * 512) + (((unsigned)(c4g * 16)) ^ (((unsigned)(p & 7)) << 4));
      const v4f t = *(const v4f*)(sH + boff);
      const u64 o8 = sOff8[p];
      const float4 w = sWl[p];
      const float4 bias = *(const float4*)(b2 + c4g * 4);
      float rx = t[0] + bias.x, ry = t[1] + bias.y, rz = t[2] + bias.z, rw = t[3] + bias.w;
      {
        const float4 f = *(const float4*)(featc + (size_t)(unsigned)(o8 & 0xFFFFu) * CC + c4g * 4);
        rx += w.x * f.x; ry += w.x * f.y; rz += w.x * f.z; rw += w.x * f.w;
      }
      {
        const float4 f =
            *(const float4*)(featc + (size_t)(unsigned)((o8 >> 16) & 0xFFFFu) * CC + c4g * 4);
        rx += w.y * f.x; ry += w.y * f.y; rz += w.y * f.z; rw += w.y * f.w;
      }
      {
        const float4 f =
            *(const float4*)(featc + (size_t)(unsigned)((o8 >> 32) & 0xFFFFu) * CC + c4g * 4);
        rx += w.z * f.x; ry += w.z * f.y; rz += w.z * f.z; rw += w.z * f.w;
      }
      {
        const float4 f =
            *(const float4*)(featc + (size_t)(unsigned)((o8 >> 48) & 0xFFFFu) * CC + c4g * 4);
        rx += w.w * f.x; ry += w.w * f.y; rz += w.w * f.z; rw += w.w * f.w;
      }
      *(float4*)(out + (size_t)(gp0 + p) * CC + c4g * 4) = make_float4(rx, ry, rz, rw);
    }
  }
}

// ---------------- last-resort fallback (no ws): fused fp32 kernel ----------------
__global__ __launch_bounds__(128) void gauss_fb(
    const float* __restrict__ means3D, const float* __restrict__ feat,
    const float* __restrict__ dvec, const float* __restrict__ cov3D,
    const float* __restrict__ l2i, const float* __restrict__ W1,
    const float* __restrict__ b1, const float* __restrict__ W2,
    const float* __restrict__ b2, float* __restrict__ out) {
  const int l = blockIdx.x;
  const int bn = blockIdx.y;
  const int tid = threadIdx.x;
  __shared__ float sH[P2][HID];
  __shared__ float sPn[P2][3];
  __shared__ float sW[P2][4];
  __shared__ int sOff[P2][4];
  if (tid < P2) {
    const int p = tid;
    const size_t base3 = ((size_t)bn * LL + l) * 3;
    const float m0 = means3D[base3 + 0], m1 = means3D[base3 + 1], m2 = means3D[base3 + 2];
    const float d0 = dvec[base3 + 0], d1 = dvec[base3 + 1], d2 = dvec[base3 + 2];
    const float* cv = cov3D + ((size_t)bn * LL + l) * 9;
    const float q = d0 * (cv[0] * d0 + cv[1] * d1 + cv[2] * d2) +
                    d1 * (cv[3] * d0 + cv[4] * d1 + cv[5] * d2) +
                    d2 * (cv[6] * d0 + cv[7] * d1 + cv[8] * d2);
    const float s = sqrtf(q);
    const int k = p >> 2, j = p & 3;
    const float a = (-1.5f + 0.75f * (float)k) * s;
    const float tt = -0.5f + (1.0f / 3.0f) * (float)j;
    const float px = m0 + a * d0 + tt * d1;
    const float py = m1 + a * d1 - tt * d0;
    const float pz = m2 + a * d2;
    const float* M = l2i + (size_t)bn * 16;
    const float cx = M[0] * px + M[1] * py + M[2] * pz + M[3];
    const float cy = M[4] * px + M[5] * py + M[6] * pz + M[7];
    const float cz = M[8] * px + M[9] * py + M[10] * pz + M[11];
    const float homo = fmaxf(cz, 1e-6f);
    const float u = cx / homo;
    const float v = cy / homo;
    float* camo = out + OUT_CAM_OFF + (((size_t)bn * LL + l) * P2 + p) * 2;
    camo[0] = u;
    camo[1] = v;
    float* ptso = out + OUT_PTS_OFF + (((size_t)bn * LL + l) * P2 + p) * 3;
    ptso[0] = px;
    ptso[1] = py;
    ptso[2] = pz;
    const float x = u * 0.125f - 0.5f;
    const float y = v * 0.125f - 0.5f;
    const float x0f = floorf(x), y0f = floorf(y);
    const float wx = x - x0f, wy = y - y0f;
    const bool vx0 = (x0f >= 0.f) && (x0f < (float)WG);
    const bool vx1 = (x0f + 1.f >= 0.f) && (x0f + 1.f < (float)WG);
    const bool vy0 = (y0f >= 0.f) && (y0f < (float)HG);
    const bool vy1 = (y0f + 1.f >= 0.f) && (y0f + 1.f < (float)HG);
    const int ix0 = (int)fminf(fmaxf(x0f, 0.f), (float)(WG - 1));
    const int ix1 = (int)fminf(fmaxf(x0f + 1.f, 0.f), (float)(WG - 1));
    const int iy0 = (int)fminf(fmaxf(y0f, 0.f), (float)(HG - 1));
    const int iy1 = (int)fminf(fmaxf(y0f + 1.f, 0.f), (float)(HG - 1));
    sOff[p][0] = iy0 * WG + ix0;
    sOff[p][1] = iy0 * WG + ix1;
    sOff[p][2] = iy1 * WG + ix0;
    sOff[p][3] = iy1 * WG + ix1;
    sW[p][0] = (vx0 && vy0) ? (1.f - wx) * (1.f - wy) : 0.f;
    sW[p][1] = (vx1 && vy0) ? wx * (1.f - wy) : 0.f;
    sW[p][2] = (vx0 && vy1) ? (1.f - wx) * wy : 0.f;
    sW[p][3] = (vx1 && vy1) ? wx * wy : 0.f;
    sPn[p][0] = fminf(fmaxf((px + 50.f) * 0.01f, 0.f), 1.f);
    sPn[p][1] = fminf(fmaxf((py + 50.f) * 0.01f, 0.f), 1.f);
    sPn[p][2] = fminf(fmaxf((pz + 4.f) * 0.125f, 0.f), 1.f);
  }
  __syncthreads();
  for (int u0 = tid; u0 < P2 * HID; u0 += 128) {
    const int p = u0 >> 8;
    const int h = u0 & (HID - 1);
    const float v = b1[h] + sPn[p][0] * W1[h] + sPn[p][1] * W1[HID + h] + sPn[p][2] * W1[2 * HID + h];
    sH[p][h] = fmaxf(v, 0.f);
  }
  __syncthreads();
  const int pg = tid >> 5;
  const int c0 = (tid & 31) * 4;
  const int pbase = pg * 5;
  float acc[5][4];
#pragma unroll
  for (int i = 0; i < 5; ++i)
#pragma unroll
    for (int j2 = 0; j2 < 4; ++j2) acc[i][j2] = 0.f;
  for (int h = 0; h < HID; h += 4) {
    const float4 w0 = *(const float4*)(W2 + (size_t)(h + 0) * CC + c0);
    const float4 w1 = *(const float4*)(W2 + (size_t)(h + 1) * CC + c0);
    const float4 w2 = *(const float4*)(W2 + (size_t)(h + 2) * CC + c0);
    const float4 w3 = *(const float4*)(W2 + (size_t)(h + 3) * CC + c0);
#pragma unroll
    for (int i = 0; i < 5; ++i) {
      const float4 hv = *(const float4*)(&sH[pbase + i][h]);
      acc[i][0] += hv.x * w0.x + hv.y * w1.x + hv.z * w2.x + hv.w * w3.x;
      acc[i][1] += hv.x * w0.y + hv.y * w1.y + hv.z * w2.y + hv.w * w3.y;
      acc[i][2] += hv.x * w0.z + hv.y * w1.z + hv.z * w2.z + hv.w * w3.z;
      acc[i][3] += hv.x * w0.w + hv.y * w1.w + hv.z * w2.w + hv.w * w3.w;
    }
  }
  const float4 bias = *(const float4*)(b2 + c0);
  const float* fbase = feat + (size_t)bn * CC * LL;
#pragma unroll
  for (int i = 0; i < 5; ++i) {
    const int p = pbase + i;
    float4 r;
    r.x = acc[i][0] + bias.x;
    r.y = acc[i][1] + bias.y;
    r.z = acc[i][2] + bias.z;
    r.w = acc[i][3] + bias.w;
#pragma unroll
    for (int corner = 0; corner < 4; ++corner) {
      const float w = sW[p][corner];
      const int off = sOff[p][corner];
      r.x += w * fbase[(size_t)(c0 + 0) * LL + off];
      r.y += w * fbase[(size_t)(c0 + 1) * LL + off];
      r.z += w * fbase[(size_t)(c0 + 2) * LL + off];
      r.w += w * fbase[(size_t)(c0 + 3) * LL + off];
    }
    *(float4*)(out + (((size_t)bn * LL + l) * P2 + p) * CC + c0) = r;
  }
}

extern "C" void kernel_launch(void* const* d_in, const int* in_sizes, int n_in,
                              void* d_out, int out_size, void* d_ws, size_t ws_size,
                              hipStream_t stream) {
  const float* means3D = (const float*)d_in[0];
  const float* img = (const float*)d_in[1];
  const float* dvec = (const float*)d_in[2];
  const float* cov3D = (const float*)d_in[3];
  const float* l2i = (const float*)d_in[4];
  const float* W1 = (const float*)d_in[5];
  const float* b1 = (const float*)d_in[6];
  const float* W2 = (const float*)d_in[7];
  const float* b2 = (const float*)d_in[8];
  float* out = (float*)d_out;

  const size_t w2bf_bytes = 65536;
  const size_t tbytes = (size_t)BN * LL * CC * sizeof(float);  // 10321920

  if (ws_size >= w2bf_bytes + tbytes) {
    unsigned short* W2bf = (unsigned short*)d_ws;
    float* featT = (float*)((char*)d_ws + w2bf_bytes);
    hipLaunchKernelGGL(prep_k, dim3(648 + 16), dim3(256), 0, stream, img, featT, W2, W2bf);
    hipLaunchKernelGGL(geom_k, dim3(NPTS / 256), dim3(256), 0, stream, means3D, dvec, cov3D,
                       l2i, out);
    hipLaunchKernelGGL(gemm_k, dim3(NWG), dim3(256), 0, stream, featT, W1, b1, W2bf, b2, out);
  } else {
    hipLaunchKernelGGL(gauss_fb, dim3(LL, BN), dim3(128), 0, stream, means3D, img, dvec, cov3D,
                       l2i, W1, b1, W2, b2, out);
  }
}